// Round 10
// baseline (741.228 us; speedup 1.0000x reference)
//
#include <hip/hip_runtime.h>
#include <hip/hip_bf16.h>
#include <math.h>

#define F_IN   2000
#define HID    16
#define HEADS  4
#define CPH    16
#define HC     64
#define NCLS   3

__device__ __forceinline__ float lrelu(float x){ return x > 0.f ? x : 0.2f*x; }

__device__ __forceinline__ float comp4(const float4& v, int k){
  return k==0 ? v.x : k==1 ? v.y : k==2 ? v.z : v.w;
}

__device__ __forceinline__ float bf2f(unsigned short u){
  return __uint_as_float(((unsigned)u) << 16);
}

// ---------------------------------------------------------------------------
// K0: zero deg (must precede fused deg-count)
// ---------------------------------------------------------------------------
__global__ void k_zero(int* __restrict__ deg, int n) {
  int i = blockIdx.x * 256 + threadIdx.x;
  if (i < n) deg[i] = 0;
}

// ---------------------------------------------------------------------------
// K1 (fused): blocks [0, ngemm): h0 = x@W1 -> bf16.
//   512 thr = 8 waves x 4 rows (block = 32 rows). TWO phases of 1000 K-rows
//   in 64KB static LDS (vs R4's four 500-row phases in 32KB): halves the
//   barrier rate and doubles resident waves (2 blocks/CU x 8 waves = 16
//   waves/CU vs 7) so stage-drain of one block overlaps compute of the
//   other. Staging/compute swizzle formulas are R4-exact.
// blocks [ngemm, ...): in-degree atomic count (rides in idle slots).
// ---------------------------------------------------------------------------
__global__ __launch_bounds__(512) void k_gemm_deg(const float* __restrict__ x,
                                                  const float* __restrict__ W1,
                                                  __hip_bfloat16* __restrict__ h0b,
                                                  int n, int ngemm,
                                                  const int* __restrict__ edst,
                                                  int* __restrict__ deg, int e) {
  __shared__ float w1s[16128];           // 4032 float4 slots = 64512 B
  if ((int)blockIdx.x >= ngemm) {        // ---- deg role ----
    int i = (blockIdx.x - ngemm) * 512 + threadIdx.x;
    if (i < e) atomicAdd(&deg[edst[i]], 1);
    return;
  }
  // ---- gemm role ----
  const int t    = threadIdx.x;
  const int lane = t & 63;
  const int wid  = t >> 6;               // 0..7
  const int rowbase = blockIdx.x * 32 + wid * 4;

  float acc[64];                         // acc[r*16 + c]
  #pragma unroll
  for (int v = 0; v < 64; ++v) acc[v] = 0.f;

  for (int phase = 0; phase < 2; ++phase) {
    const int kbase = phase * 1000;
    __syncthreads();
    // stage 1000 rows (4000 float4 slots): 8 gll per wave, linear LDS dest,
    // pre-swizzled global source (R4-exact involution).
    #pragma unroll
    for (int k = 0; k < 8; ++k) {
      const int slotbase = wid * 512 + k * 64;      // wave-uniform
      if (slotbase < 4000) {
        const int slot = slotbase + lane;
        const int row_slot = slot >> 2;
        const int r = row_slot ^ ((row_slot >> 4) & 1);
        const int q = (slot & 3) ^ ((row_slot >> 2) & 3);
        int rg = kbase + r;
        if (rg > 1999) rg = 1999;                   // clamp; junk slots unread
        __builtin_amdgcn_global_load_lds(
            (const __attribute__((address_space(1))) void*)(W1 + (size_t)rg * 16 + q * 4),
            (__attribute__((address_space(3))) void*)(w1s + (size_t)slotbase * 4),
            16, 0, 0);
      }
    }
    __syncthreads();                                // drains vmcnt -> LDS ready

    #pragma unroll
    for (int ci = 0; ci < 4; ++ci) {
      int f4l = ci * 64 + lane;           // phase-local float4-of-K, <250 valid
      if (f4l < 250) {
        float4 xv[4];
        #pragma unroll
        for (int r = 0; r < 4; ++r) {
          int row = rowbase + r;
          xv[r] = (row < n)
              ? *reinterpret_cast<const float4*>(
                    x + (size_t)row * F_IN + kbase + f4l * 4)
              : make_float4(0.f, 0.f, 0.f, 0.f);
        }
        const int qx = f4l & 3;
        const int xb = (f4l >> 2) & 1;
        #pragma unroll
        for (int kk = 0; kk < 4; ++kk) {
          const int rs = (4 * f4l + kk) ^ xb;       // swizzled row slot
          const float* rowp = w1s + rs * 16;
          float xk0 = comp4(xv[0], kk), xk1 = comp4(xv[1], kk);
          float xk2 = comp4(xv[2], kk), xk3 = comp4(xv[3], kk);
          #pragma unroll
          for (int q = 0; q < 4; ++q) {
            float4 w4 = *reinterpret_cast<const float4*>(rowp + ((q ^ qx) << 2));
            acc[0*16+4*q+0] += xk0 * w4.x; acc[0*16+4*q+1] += xk0 * w4.y;
            acc[0*16+4*q+2] += xk0 * w4.z; acc[0*16+4*q+3] += xk0 * w4.w;
            acc[1*16+4*q+0] += xk1 * w4.x; acc[1*16+4*q+1] += xk1 * w4.y;
            acc[1*16+4*q+2] += xk1 * w4.z; acc[1*16+4*q+3] += xk1 * w4.w;
            acc[2*16+4*q+0] += xk2 * w4.x; acc[2*16+4*q+1] += xk2 * w4.y;
            acc[2*16+4*q+2] += xk2 * w4.z; acc[2*16+4*q+3] += xk2 * w4.w;
            acc[3*16+4*q+0] += xk3 * w4.x; acc[3*16+4*q+1] += xk3 * w4.y;
            acc[3*16+4*q+2] += xk3 * w4.z; acc[3*16+4*q+3] += xk3 * w4.w;
          }
        }
      }
    }
  }

  // reduce-scatter across 64 lanes: final acc[0] = full sum for value v=lane,
  // lane layout (r=lane>>4, c=lane&15).
  #pragma unroll
  for (int b = 32; b >= 1; b >>= 1) {
    bool hi = (lane & b) != 0;
    #pragma unroll
    for (int j = 0; j < b; ++j) {
      float send = hi ? acc[j] : acc[b + j];
      float recv = __shfl_xor(send, b);
      acc[j] = (hi ? acc[b + j] : acc[j]) + recv;
    }
  }
  int r = lane >> 4, c = lane & 15;
  int row = rowbase + r;
  if (row < n) h0b[(size_t)row * 16 + c] = __float2bfloat16(acc[0]);
}

// ---------------------------------------------------------------------------
// K3a/b/c: exclusive prefix scan of deg -> rowptr (+cursor); dinv
// ---------------------------------------------------------------------------
__global__ void k_scan_a(const int* __restrict__ deg, int* __restrict__ bsum, int n) {
  __shared__ int s[256];
  int i = blockIdx.x * 256 + threadIdx.x;
  s[threadIdx.x] = (i < n) ? deg[i] : 0;
  __syncthreads();
  for (int off = 128; off > 0; off >>= 1) {
    if (threadIdx.x < off) s[threadIdx.x] += s[threadIdx.x + off];
    __syncthreads();
  }
  if (threadIdx.x == 0) bsum[blockIdx.x] = s[0];
}

__global__ void k_scan_b(int* __restrict__ bsum, int nb) {
  int lane = threadIdx.x;   // 64 threads
  int carry = 0;
  for (int base = 0; base < nb; base += 64) {
    int idx = base + lane;
    int orig = (idx < nb) ? bsum[idx] : 0;
    int v = orig;
    #pragma unroll
    for (int off = 1; off < 64; off <<= 1) {
      int tv = __shfl_up(v, off);
      if (lane >= off) v += tv;
    }
    if (idx < nb) bsum[idx] = carry + v - orig;   // exclusive
    carry += __shfl(v, 63);
  }
}

__global__ void k_scan_c(const int* __restrict__ deg, const int* __restrict__ bsum,
                         int* __restrict__ rowptr, int* __restrict__ cursor,
                         float* __restrict__ dinv, int n) {
  __shared__ int s[256];
  int i = blockIdx.x * 256 + threadIdx.x;
  int v = (i < n) ? deg[i] : 0;
  s[threadIdx.x] = v;
  __syncthreads();
  for (int off = 1; off < 256; off <<= 1) {
    int tv = (threadIdx.x >= off) ? s[threadIdx.x - off] : 0;
    __syncthreads();
    s[threadIdx.x] += tv;
    __syncthreads();
  }
  int excl = s[threadIdx.x] - v + bsum[blockIdx.x];
  if (i < n) {
    rowptr[i] = excl;
    cursor[i] = excl;
    dinv[i] = rsqrtf((float)(v + 1));
    if (i == n - 1) rowptr[n] = excl + v;
  }
}

// ---------------------------------------------------------------------------
// K4: scatter edges into CSR
// ---------------------------------------------------------------------------
__global__ void k_scatter(const int* __restrict__ esrc, const int* __restrict__ edst,
                          int* __restrict__ cursor, int* __restrict__ csr, int e) {
  int i = blockIdx.x * 256 + threadIdx.x;
  if (i < e) {
    int d = edst[i];
    int pos = atomicAdd(&cursor[d], 1);
    csr[pos] = esrc[i];
  }
}

// ---------------------------------------------------------------------------
// K5: per-dst GCN aggregate + bias + relu, g = h@Wg (bf16 out), a_s/a_d dots.
// ---------------------------------------------------------------------------
__global__ __launch_bounds__(256) void k_gcn(
    const unsigned short* __restrict__ h0b, const int* __restrict__ rowptr,
    const int* __restrict__ csr, const float* __restrict__ dinv,
    const float* __restrict__ b1, const float* __restrict__ Wg,
    const float* __restrict__ atts, const float* __restrict__ attd,
    __hip_bfloat16* __restrict__ gb, float* __restrict__ a_s,
    float* __restrict__ a_d, int n) {
  __shared__ float wgs[HID * HC];
  __shared__ float ats[HC], atd[HC];
  int t = threadIdx.x;
  for (int i = t; i < HID * HC; i += 256) wgs[i] = Wg[i];
  if (t < HC) { ats[t] = atts[t]; atd[t] = attd[t]; }
  __syncthreads();

  int lane = t & 63, w = t >> 6;
  int dst = blockIdx.x * 4 + w;
  if (dst >= n) return;
  int j = lane >> 4, c = lane & 15;
  int start = rowptr[dst], end = rowptr[dst + 1];
  float dd = dinv[dst];

  float acc = 0.f;
  for (int idx = start + j; idx < end; idx += 4) {
    int src = csr[idx];
    acc += bf2f(h0b[(size_t)src * 16 + c]) * dinv[src];
  }
  acc += __shfl_xor(acc, 16);
  acc += __shfl_xor(acc, 32);
  acc = acc * dd + bf2f(h0b[(size_t)dst * 16 + c]) * dd * dd;  // + self loop
  float hv = fmaxf(acc + b1[c], 0.f);

  float go = 0.f;
  #pragma unroll
  for (int k = 0; k < 16; ++k) {
    float hk = __shfl(hv, k);
    go += hk * wgs[k * HC + lane];
  }
  gb[(size_t)dst * HC + lane] = __float2bfloat16(go);

  float asv = go * ats[lane], adv = go * atd[lane];
  #pragma unroll
  for (int m = 1; m < 16; m <<= 1) {
    asv += __shfl_xor(asv, m);
    adv += __shfl_xor(adv, m);
  }
  if (c == 0) {
    a_s[(size_t)dst * 4 + j] = asv;
    a_d[(size_t)dst * 4 + j] = adv;
  }
}

// ---------------------------------------------------------------------------
// K6: per-dst GAT, SINGLE online-softmax edge sweep + classifier + log_softmax.
// ---------------------------------------------------------------------------
__global__ __launch_bounds__(256) void k_gat(
    const unsigned short* __restrict__ gb, const int* __restrict__ rowptr,
    const int* __restrict__ csr, const float* __restrict__ a_s,
    const float* __restrict__ a_d, const float* __restrict__ bg,
    const float* __restrict__ Wo, const float* __restrict__ bo,
    float* __restrict__ out, int n) {
  __shared__ float wos[HC * NCLS];
  __shared__ float bgs[HC];
  __shared__ float bos[NCLS];
  int t = threadIdx.x;
  if (t < HC * NCLS) wos[t] = Wo[t];
  if (t < HC) bgs[t] = bg[t];
  if (t < NCLS) bos[t] = bo[t];
  __syncthreads();

  int lane = t & 63, w = t >> 6;
  int dst = blockIdx.x * 4 + w;
  if (dst >= n) return;
  int start = rowptr[dst], end = rowptr[dst + 1];
  int j = lane >> 4, c = lane & 15, h = c >> 2;

  float adh = a_d[(size_t)dst * 4 + h];
  float ash = a_s[(size_t)dst * 4 + h];

  float m = -1e30f, den = 0.f;
  float a0 = 0.f, a1 = 0.f, a2 = 0.f, a3 = 0.f;

  for (int idx = start + j; idx < end; idx += 4) {
    int src = csr[idx];
    float e = lrelu(a_s[(size_t)src * 4 + h] + adh);
    float mn = fmaxf(m, e);
    float corr = __expf(m - mn);          // 1 when no new max
    float p = __expf(e - mn);
    ushort4 u4 = *reinterpret_cast<const ushort4*>(gb + (size_t)src * HC + c * 4);
    den = den * corr + p;
    a0 = a0 * corr + p * bf2f(u4.x);
    a1 = a1 * corr + p * bf2f(u4.y);
    a2 = a2 * corr + p * bf2f(u4.z);
    a3 = a3 * corr + p * bf2f(u4.w);
    m = mn;
  }
  if (j == 0) {                            // self loop, counted once
    float e = lrelu(ash + adh);
    float mn = fmaxf(m, e);
    float corr = __expf(m - mn);
    float p = __expf(e - mn);
    ushort4 u4 = *reinterpret_cast<const ushort4*>(gb + (size_t)dst * HC + c * 4);
    den = den * corr + p;
    a0 = a0 * corr + p * bf2f(u4.x);
    a1 = a1 * corr + p * bf2f(u4.y);
    a2 = a2 * corr + p * bf2f(u4.z);
    a3 = a3 * corr + p * bf2f(u4.w);
    m = mn;
  }

  // merge the 4 j-stripes (lanes differing in bits 4,5)
  #pragma unroll
  for (int msk = 16; msk <= 32; msk <<= 1) {
    float m2 = __shfl_xor(m, msk);
    float d2 = __shfl_xor(den, msk);
    float b0 = __shfl_xor(a0, msk);
    float b1v = __shfl_xor(a1, msk);
    float b2 = __shfl_xor(a2, msk);
    float b3 = __shfl_xor(a3, msk);
    float M = fmaxf(m, m2);
    float c1 = __expf(m - M), c2 = __expf(m2 - M);
    den = den * c1 + d2 * c2;
    a0 = a0 * c1 + b0 * c2;
    a1 = a1 * c1 + b1v * c2;
    a2 = a2 * c1 + b2 * c2;
    a3 = a3 * c1 + b3 * c2;
    m = M;
  }
  den += 1e-16f;

  float o0 = a0 / den + bgs[c * 4 + 0];
  float o1 = a1 / den + bgs[c * 4 + 1];
  float o2 = a2 / den + bgs[c * 4 + 2];
  float o3 = a3 / den + bgs[c * 4 + 3];

  float p0 = 0.f, p1 = 0.f, p2 = 0.f;
  {
    int ch = c * 4;
    p0 += o0 * wos[(ch+0)*NCLS+0] + o1 * wos[(ch+1)*NCLS+0] + o2 * wos[(ch+2)*NCLS+0] + o3 * wos[(ch+3)*NCLS+0];
    p1 += o0 * wos[(ch+0)*NCLS+1] + o1 * wos[(ch+1)*NCLS+1] + o2 * wos[(ch+2)*NCLS+1] + o3 * wos[(ch+3)*NCLS+1];
    p2 += o0 * wos[(ch+0)*NCLS+2] + o1 * wos[(ch+1)*NCLS+2] + o2 * wos[(ch+2)*NCLS+2] + o3 * wos[(ch+3)*NCLS+2];
  }
  #pragma unroll
  for (int msk = 1; msk < 16; msk <<= 1) {
    p0 += __shfl_xor(p0, msk);
    p1 += __shfl_xor(p1, msk);
    p2 += __shfl_xor(p2, msk);
  }
  p0 += bos[0]; p1 += bos[1]; p2 += bos[2];
  float mx = fmaxf(p0, fmaxf(p1, p2));
  float ls = mx + logf(__expf(p0 - mx) + __expf(p1 - mx) + __expf(p2 - mx));
  if (lane == 0) {
    out[(size_t)dst * 3 + 0] = p0 - ls;
    out[(size_t)dst * 3 + 1] = p1 - ls;
    out[(size_t)dst * 3 + 2] = p2 - ls;
  }
}

// ---------------------------------------------------------------------------
extern "C" void kernel_launch(void* const* d_in, const int* in_sizes, int n_in,
                              void* d_out, int out_size, void* d_ws, size_t ws_size,
                              hipStream_t stream) {
  const float* x    = (const float*)d_in[0];
  const int*   ei   = (const int*)  d_in[1];
  const float* W1   = (const float*)d_in[2];
  const float* b1   = (const float*)d_in[3];
  const float* Wg   = (const float*)d_in[4];
  const float* atts = (const float*)d_in[5];
  const float* attd = (const float*)d_in[6];
  const float* bg   = (const float*)d_in[7];
  const float* Wo   = (const float*)d_in[8];
  const float* bo   = (const float*)d_in[9];
  float* out = (float*)d_out;

  const int n = in_sizes[0] / F_IN;
  const int e = in_sizes[1] / 2;
  const int* esrc = ei;
  const int* edst = ei + e;

  char* p = (char*)d_ws;
  auto alloc = [&](size_t bytes) { char* r = p; p += (bytes + 255) & ~(size_t)255; return r; };
  __hip_bfloat16* h0b = (__hip_bfloat16*)alloc((size_t)n * 16 * 2);
  int*   deg    = (int*)  alloc((size_t)n * 4);
  int*   cursor = (int*)  alloc((size_t)n * 4);
  float* dinv   = (float*)alloc((size_t)n * 4);
  int*   rowptr = (int*)  alloc((size_t)(n + 1) * 4);
  int*   bsum   = (int*)  alloc(4096);
  int*   csr    = (int*)  alloc((size_t)e * 4);
  __hip_bfloat16* gbuf = (__hip_bfloat16*)alloc((size_t)n * HC * 2);
  float* as_    = (float*)alloc((size_t)n * 4 * 4);
  float* ad_    = (float*)alloc((size_t)n * 4 * 4);

  int nzb = (n + 255) / 256;
  k_zero<<<nzb, 256, 0, stream>>>(deg, n);

  const int ngemm = (n + 31) / 32;
  const int ndeg  = (e + 511) / 512;
  k_gemm_deg<<<ngemm + ndeg, 512, 0, stream>>>(x, W1, h0b, n, ngemm, edst, deg, e);

  int nb = (n + 255) / 256;
  k_scan_a<<<nb, 256, 0, stream>>>(deg, bsum, n);
  k_scan_b<<<1, 64, 0, stream>>>(bsum, nb);
  k_scan_c<<<nb, 256, 0, stream>>>(deg, bsum, rowptr, cursor, dinv, n);

  k_scatter<<<(e + 255) / 256, 256, 0, stream>>>(esrc, edst, cursor, csr, e);

  k_gcn<<<(n + 3) / 4, 256, 0, stream>>>((const unsigned short*)h0b, rowptr, csr,
                                         dinv, b1, Wg, atts, attd,
                                         gbuf, as_, ad_, n);

  k_gat<<<(n + 3) / 4, 256, 0, stream>>>((const unsigned short*)gbuf, rowptr, csr,
                                         as_, ad_, bg, Wo, bo, out, n);
}

// Round 11
// 433.051 us; speedup vs baseline: 1.7116x; 1.7116x over previous
//
#include <hip/hip_runtime.h>
#include <hip/hip_bf16.h>
#include <math.h>

#define F_IN   2000
#define HID    16
#define HEADS  4
#define CPH    16
#define HC     64
#define NCLS   3

__device__ __forceinline__ float lrelu(float x){ return x > 0.f ? x : 0.2f*x; }

__device__ __forceinline__ float comp4(const float4& v, int k){
  return k==0 ? v.x : k==1 ? v.y : k==2 ? v.z : v.w;
}

__device__ __forceinline__ float bf2f(unsigned short u){
  return __uint_as_float(((unsigned)u) << 16);
}

// ---------------------------------------------------------------------------
// K0: zero deg (must precede fused deg-count)
// ---------------------------------------------------------------------------
__global__ void k_zero(int* __restrict__ deg, int n) {
  int i = blockIdx.x * 256 + threadIdx.x;
  if (i < n) deg[i] = 0;
}

// ---------------------------------------------------------------------------
// K1 (fused, R9 structure): blocks [0, ngemm): h0 = x@W1 -> bf16
//   (256 thr = 4 waves x 4 rows, 4 phases of 500 rows, 32KB LDS,
//   global_load_lds staging w/ pre-swizzled source). ONE change vs R9:
//   both chunks' x-loads (8 float4/lane) are issued BEFORE the stage-drain
//   barrier, so x HBM latency overlaps the gll drain (2x in-flight bytes).
// blocks [ngemm, ...): in-degree atomic count (rides in idle slots).
// ---------------------------------------------------------------------------
__global__ __launch_bounds__(256) void k_gemm_deg(const float* __restrict__ x,
                                                  const float* __restrict__ W1,
                                                  __hip_bfloat16* __restrict__ h0b,
                                                  int n, int ngemm,
                                                  const int* __restrict__ edst,
                                                  int* __restrict__ deg, int e) {
  __shared__ float w1s[8192];            // 512 rows x 16 floats (swizzled)
  if ((int)blockIdx.x >= ngemm) {        // ---- deg role ----
    int i = (blockIdx.x - ngemm) * 256 + threadIdx.x;
    if (i < e) atomicAdd(&deg[edst[i]], 1);
    return;
  }
  // ---- gemm role ----
  const int t    = threadIdx.x;
  const int lane = t & 63;
  const int wid  = t >> 6;               // 0..3
  const int rowbase = blockIdx.x * 16 + wid * 4;

  float acc[64];                         // acc[r*16 + c]
  #pragma unroll
  for (int v = 0; v < 64; ++v) acc[v] = 0.f;

  for (int phase = 0; phase < 4; ++phase) {
    const int kbase = phase * 500;
    __syncthreads();                     // all waves done reading prev phase
    // stage 500 rows (2000 float4 slots): 8 gll per wave, linear LDS dest,
    // pre-swizzled global source (R4-exact involution).
    #pragma unroll
    for (int k = 0; k < 8; ++k) {
      const int slotbase = (wid * 8 + k) * 64;      // wave-uniform
      const int slot = slotbase + lane;
      const int row_slot = slot >> 2;
      const int r = row_slot ^ ((row_slot >> 4) & 1);
      const int q = (slot & 3) ^ ((row_slot >> 2) & 3);
      int rg = kbase + r;
      if (rg > 1999) rg = 1999;                     // clamp; junk slots unread
      __builtin_amdgcn_global_load_lds(
          (const __attribute__((address_space(1))) void*)(W1 + (size_t)rg * 16 + q * 4),
          (__attribute__((address_space(3))) void*)(w1s + (size_t)slotbase * 4),
          16, 0, 0);
    }
    // issue BOTH chunks' x loads now -- latency hides under the gll drain
    float4 xv[2][4];
    #pragma unroll
    for (int i = 0; i < 2; ++i) {
      const int f4l = i * 64 + lane;
      const bool kv = (f4l < 125);
      #pragma unroll
      for (int r = 0; r < 4; ++r) {
        int row = rowbase + r;
        xv[i][r] = (kv && row < n)
            ? *reinterpret_cast<const float4*>(
                  x + (size_t)row * F_IN + kbase + f4l * 4)
            : make_float4(0.f, 0.f, 0.f, 0.f);
      }
    }
    __syncthreads();                                // drains vmcnt -> LDS + x ready

    #pragma unroll
    for (int i = 0; i < 2; ++i) {
      int f4l = i * 64 + lane;            // local float4-of-K index, <125 valid
      if (f4l < 125) {
        const int qx = f4l & 3;
        const int xb = (f4l >> 2) & 1;
        #pragma unroll
        for (int kk = 0; kk < 4; ++kk) {
          const int rs = (4 * f4l + kk) ^ xb;       // swizzled row slot
          const float* rowp = w1s + rs * 16;
          float xk0 = comp4(xv[i][0], kk), xk1 = comp4(xv[i][1], kk);
          float xk2 = comp4(xv[i][2], kk), xk3 = comp4(xv[i][3], kk);
          #pragma unroll
          for (int q = 0; q < 4; ++q) {
            float4 w4 = *reinterpret_cast<const float4*>(rowp + ((q ^ qx) << 2));
            acc[0*16+4*q+0] += xk0 * w4.x; acc[0*16+4*q+1] += xk0 * w4.y;
            acc[0*16+4*q+2] += xk0 * w4.z; acc[0*16+4*q+3] += xk0 * w4.w;
            acc[1*16+4*q+0] += xk1 * w4.x; acc[1*16+4*q+1] += xk1 * w4.y;
            acc[1*16+4*q+2] += xk1 * w4.z; acc[1*16+4*q+3] += xk1 * w4.w;
            acc[2*16+4*q+0] += xk2 * w4.x; acc[2*16+4*q+1] += xk2 * w4.y;
            acc[2*16+4*q+2] += xk2 * w4.z; acc[2*16+4*q+3] += xk2 * w4.w;
            acc[3*16+4*q+0] += xk3 * w4.x; acc[3*16+4*q+1] += xk3 * w4.y;
            acc[3*16+4*q+2] += xk3 * w4.z; acc[3*16+4*q+3] += xk3 * w4.w;
          }
        }
      }
    }
  }

  // reduce-scatter across 64 lanes: final acc[0] = full sum for value v=lane,
  // lane layout (r=lane>>4, c=lane&15).
  #pragma unroll
  for (int b = 32; b >= 1; b >>= 1) {
    bool hi = (lane & b) != 0;
    #pragma unroll
    for (int j = 0; j < b; ++j) {
      float send = hi ? acc[j] : acc[b + j];
      float recv = __shfl_xor(send, b);
      acc[j] = (hi ? acc[b + j] : acc[j]) + recv;
    }
  }
  int r = lane >> 4, c = lane & 15;
  int row = rowbase + r;
  if (row < n) h0b[(size_t)row * 16 + c] = __float2bfloat16(acc[0]);
}

// ---------------------------------------------------------------------------
// K3a/b/c: exclusive prefix scan of deg -> rowptr (+cursor); dinv
// ---------------------------------------------------------------------------
__global__ void k_scan_a(const int* __restrict__ deg, int* __restrict__ bsum, int n) {
  __shared__ int s[256];
  int i = blockIdx.x * 256 + threadIdx.x;
  s[threadIdx.x] = (i < n) ? deg[i] : 0;
  __syncthreads();
  for (int off = 128; off > 0; off >>= 1) {
    if (threadIdx.x < off) s[threadIdx.x] += s[threadIdx.x + off];
    __syncthreads();
  }
  if (threadIdx.x == 0) bsum[blockIdx.x] = s[0];
}

__global__ void k_scan_b(int* __restrict__ bsum, int nb) {
  int lane = threadIdx.x;   // 64 threads
  int carry = 0;
  for (int base = 0; base < nb; base += 64) {
    int idx = base + lane;
    int orig = (idx < nb) ? bsum[idx] : 0;
    int v = orig;
    #pragma unroll
    for (int off = 1; off < 64; off <<= 1) {
      int tv = __shfl_up(v, off);
      if (lane >= off) v += tv;
    }
    if (idx < nb) bsum[idx] = carry + v - orig;   // exclusive
    carry += __shfl(v, 63);
  }
}

__global__ void k_scan_c(const int* __restrict__ deg, const int* __restrict__ bsum,
                         int* __restrict__ rowptr, int* __restrict__ cursor,
                         float* __restrict__ dinv, int n) {
  __shared__ int s[256];
  int i = blockIdx.x * 256 + threadIdx.x;
  int v = (i < n) ? deg[i] : 0;
  s[threadIdx.x] = v;
  __syncthreads();
  for (int off = 1; off < 256; off <<= 1) {
    int tv = (threadIdx.x >= off) ? s[threadIdx.x - off] : 0;
    __syncthreads();
    s[threadIdx.x] += tv;
    __syncthreads();
  }
  int excl = s[threadIdx.x] - v + bsum[blockIdx.x];
  if (i < n) {
    rowptr[i] = excl;
    cursor[i] = excl;
    dinv[i] = rsqrtf((float)(v + 1));
    if (i == n - 1) rowptr[n] = excl + v;
  }
}

// ---------------------------------------------------------------------------
// K4: scatter edges into CSR
// ---------------------------------------------------------------------------
__global__ void k_scatter(const int* __restrict__ esrc, const int* __restrict__ edst,
                          int* __restrict__ cursor, int* __restrict__ csr, int e) {
  int i = blockIdx.x * 256 + threadIdx.x;
  if (i < e) {
    int d = edst[i];
    int pos = atomicAdd(&cursor[d], 1);
    csr[pos] = esrc[i];
  }
}

// ---------------------------------------------------------------------------
// K5: per-dst GCN aggregate + bias + relu, g = h@Wg (bf16 out), a_s/a_d dots.
// ---------------------------------------------------------------------------
__global__ __launch_bounds__(256) void k_gcn(
    const unsigned short* __restrict__ h0b, const int* __restrict__ rowptr,
    const int* __restrict__ csr, const float* __restrict__ dinv,
    const float* __restrict__ b1, const float* __restrict__ Wg,
    const float* __restrict__ atts, const float* __restrict__ attd,
    __hip_bfloat16* __restrict__ gb, float* __restrict__ a_s,
    float* __restrict__ a_d, int n) {
  __shared__ float wgs[HID * HC];
  __shared__ float ats[HC], atd[HC];
  int t = threadIdx.x;
  for (int i = t; i < HID * HC; i += 256) wgs[i] = Wg[i];
  if (t < HC) { ats[t] = atts[t]; atd[t] = attd[t]; }
  __syncthreads();

  int lane = t & 63, w = t >> 6;
  int dst = blockIdx.x * 4 + w;
  if (dst >= n) return;
  int j = lane >> 4, c = lane & 15;
  int start = rowptr[dst], end = rowptr[dst + 1];
  float dd = dinv[dst];

  float acc = 0.f;
  for (int idx = start + j; idx < end; idx += 4) {
    int src = csr[idx];
    acc += bf2f(h0b[(size_t)src * 16 + c]) * dinv[src];
  }
  acc += __shfl_xor(acc, 16);
  acc += __shfl_xor(acc, 32);
  acc = acc * dd + bf2f(h0b[(size_t)dst * 16 + c]) * dd * dd;  // + self loop
  float hv = fmaxf(acc + b1[c], 0.f);

  float go = 0.f;
  #pragma unroll
  for (int k = 0; k < 16; ++k) {
    float hk = __shfl(hv, k);
    go += hk * wgs[k * HC + lane];
  }
  gb[(size_t)dst * HC + lane] = __float2bfloat16(go);

  float asv = go * ats[lane], adv = go * atd[lane];
  #pragma unroll
  for (int m = 1; m < 16; m <<= 1) {
    asv += __shfl_xor(asv, m);
    adv += __shfl_xor(adv, m);
  }
  if (c == 0) {
    a_s[(size_t)dst * 4 + j] = asv;
    a_d[(size_t)dst * 4 + j] = adv;
  }
}

// ---------------------------------------------------------------------------
// K6: per-dst GAT, SINGLE online-softmax edge sweep + classifier + log_softmax.
// ---------------------------------------------------------------------------
__global__ __launch_bounds__(256) void k_gat(
    const unsigned short* __restrict__ gb, const int* __restrict__ rowptr,
    const int* __restrict__ csr, const float* __restrict__ a_s,
    const float* __restrict__ a_d, const float* __restrict__ bg,
    const float* __restrict__ Wo, const float* __restrict__ bo,
    float* __restrict__ out, int n) {
  __shared__ float wos[HC * NCLS];
  __shared__ float bgs[HC];
  __shared__ float bos[NCLS];
  int t = threadIdx.x;
  if (t < HC * NCLS) wos[t] = Wo[t];
  if (t < HC) bgs[t] = bg[t];
  if (t < NCLS) bos[t] = bo[t];
  __syncthreads();

  int lane = t & 63, w = t >> 6;
  int dst = blockIdx.x * 4 + w;
  if (dst >= n) return;
  int start = rowptr[dst], end = rowptr[dst + 1];
  int j = lane >> 4, c = lane & 15, h = c >> 2;

  float adh = a_d[(size_t)dst * 4 + h];
  float ash = a_s[(size_t)dst * 4 + h];

  float m = -1e30f, den = 0.f;
  float a0 = 0.f, a1 = 0.f, a2 = 0.f, a3 = 0.f;

  for (int idx = start + j; idx < end; idx += 4) {
    int src = csr[idx];
    float e = lrelu(a_s[(size_t)src * 4 + h] + adh);
    float mn = fmaxf(m, e);
    float corr = __expf(m - mn);          // 1 when no new max
    float p = __expf(e - mn);
    ushort4 u4 = *reinterpret_cast<const ushort4*>(gb + (size_t)src * HC + c * 4);
    den = den * corr + p;
    a0 = a0 * corr + p * bf2f(u4.x);
    a1 = a1 * corr + p * bf2f(u4.y);
    a2 = a2 * corr + p * bf2f(u4.z);
    a3 = a3 * corr + p * bf2f(u4.w);
    m = mn;
  }
  if (j == 0) {                            // self loop, counted once
    float e = lrelu(ash + adh);
    float mn = fmaxf(m, e);
    float corr = __expf(m - mn);
    float p = __expf(e - mn);
    ushort4 u4 = *reinterpret_cast<const ushort4*>(gb + (size_t)dst * HC + c * 4);
    den = den * corr + p;
    a0 = a0 * corr + p * bf2f(u4.x);
    a1 = a1 * corr + p * bf2f(u4.y);
    a2 = a2 * corr + p * bf2f(u4.z);
    a3 = a3 * corr + p * bf2f(u4.w);
    m = mn;
  }

  // merge the 4 j-stripes (lanes differing in bits 4,5)
  #pragma unroll
  for (int msk = 16; msk <= 32; msk <<= 1) {
    float m2 = __shfl_xor(m, msk);
    float d2 = __shfl_xor(den, msk);
    float b0 = __shfl_xor(a0, msk);
    float b1v = __shfl_xor(a1, msk);
    float b2 = __shfl_xor(a2, msk);
    float b3 = __shfl_xor(a3, msk);
    float M = fmaxf(m, m2);
    float c1 = __expf(m - M), c2 = __expf(m2 - M);
    den = den * c1 + d2 * c2;
    a0 = a0 * c1 + b0 * c2;
    a1 = a1 * c1 + b1v * c2;
    a2 = a2 * c1 + b2 * c2;
    a3 = a3 * c1 + b3 * c2;
    m = M;
  }
  den += 1e-16f;

  float o0 = a0 / den + bgs[c * 4 + 0];
  float o1 = a1 / den + bgs[c * 4 + 1];
  float o2 = a2 / den + bgs[c * 4 + 2];
  float o3 = a3 / den + bgs[c * 4 + 3];

  float p0 = 0.f, p1 = 0.f, p2 = 0.f;
  {
    int ch = c * 4;
    p0 += o0 * wos[(ch+0)*NCLS+0] + o1 * wos[(ch+1)*NCLS+0] + o2 * wos[(ch+2)*NCLS+0] + o3 * wos[(ch+3)*NCLS+0];
    p1 += o0 * wos[(ch+0)*NCLS+1] + o1 * wos[(ch+1)*NCLS+1] + o2 * wos[(ch+2)*NCLS+1] + o3 * wos[(ch+3)*NCLS+1];
    p2 += o0 * wos[(ch+0)*NCLS+2] + o1 * wos[(ch+1)*NCLS+2] + o2 * wos[(ch+2)*NCLS+2] + o3 * wos[(ch+3)*NCLS+2];
  }
  #pragma unroll
  for (int msk = 1; msk < 16; msk <<= 1) {
    p0 += __shfl_xor(p0, msk);
    p1 += __shfl_xor(p1, msk);
    p2 += __shfl_xor(p2, msk);
  }
  p0 += bos[0]; p1 += bos[1]; p2 += bos[2];
  float mx = fmaxf(p0, fmaxf(p1, p2));
  float ls = mx + logf(__expf(p0 - mx) + __expf(p1 - mx) + __expf(p2 - mx));
  if (lane == 0) {
    out[(size_t)dst * 3 + 0] = p0 - ls;
    out[(size_t)dst * 3 + 1] = p1 - ls;
    out[(size_t)dst * 3 + 2] = p2 - ls;
  }
}

// ---------------------------------------------------------------------------
extern "C" void kernel_launch(void* const* d_in, const int* in_sizes, int n_in,
                              void* d_out, int out_size, void* d_ws, size_t ws_size,
                              hipStream_t stream) {
  const float* x    = (const float*)d_in[0];
  const int*   ei   = (const int*)  d_in[1];
  const float* W1   = (const float*)d_in[2];
  const float* b1   = (const float*)d_in[3];
  const float* Wg   = (const float*)d_in[4];
  const float* atts = (const float*)d_in[5];
  const float* attd = (const float*)d_in[6];
  const float* bg   = (const float*)d_in[7];
  const float* Wo   = (const float*)d_in[8];
  const float* bo   = (const float*)d_in[9];
  float* out = (float*)d_out;

  const int n = in_sizes[0] / F_IN;
  const int e = in_sizes[1] / 2;
  const int* esrc = ei;
  const int* edst = ei + e;

  char* p = (char*)d_ws;
  auto alloc = [&](size_t bytes) { char* r = p; p += (bytes + 255) & ~(size_t)255; return r; };
  __hip_bfloat16* h0b = (__hip_bfloat16*)alloc((size_t)n * 16 * 2);
  int*   deg    = (int*)  alloc((size_t)n * 4);
  int*   cursor = (int*)  alloc((size_t)n * 4);
  float* dinv   = (float*)alloc((size_t)n * 4);
  int*   rowptr = (int*)  alloc((size_t)(n + 1) * 4);
  int*   bsum   = (int*)  alloc(4096);
  int*   csr    = (int*)  alloc((size_t)e * 4);
  __hip_bfloat16* gbuf = (__hip_bfloat16*)alloc((size_t)n * HC * 2);
  float* as_    = (float*)alloc((size_t)n * 4 * 4);
  float* ad_    = (float*)alloc((size_t)n * 4 * 4);

  int nzb = (n + 255) / 256;
  k_zero<<<nzb, 256, 0, stream>>>(deg, n);

  const int ngemm = (n + 15) / 16;
  const int ndeg  = (e + 255) / 256;
  k_gemm_deg<<<ngemm + ndeg, 256, 0, stream>>>(x, W1, h0b, n, ngemm, edst, deg, e);

  int nb = (n + 255) / 256;
  k_scan_a<<<nb, 256, 0, stream>>>(deg, bsum, n);
  k_scan_b<<<1, 64, 0, stream>>>(bsum, nb);
  k_scan_c<<<nb, 256, 0, stream>>>(deg, bsum, rowptr, cursor, dinv, n);

  k_scatter<<<(e + 255) / 256, 256, 0, stream>>>(esrc, edst, cursor, csr, e);

  k_gcn<<<(n + 3) / 4, 256, 0, stream>>>((const unsigned short*)h0b, rowptr, csr,
                                         dinv, b1, Wg, atts, attd,
                                         gbuf, as_, ad_, n);

  k_gat<<<(n + 3) / 4, 256, 0, stream>>>((const unsigned short*)gbuf, rowptr, csr,
                                         as_, ad_, bg, Wo, bo, out, n);
}